// Round 1
// baseline (358.811 us; speedup 1.0000x reference)
//
#include <hip/hip_runtime.h>
#include <hip/hip_bf16.h>

// B=8, S=512 -> TOK=4096 tokens, D=1024, F=2048, H=16 heads, O=1.
#define TOK 4096
#define DD  1024
#define FF  2048
#define NH  16

typedef short bf16x8 __attribute__((ext_vector_type(8)));
typedef float f32x4  __attribute__((ext_vector_type(4)));

__device__ __forceinline__ float gelu_f(float x) {
  float u = 0.7978845608028654f * (x + 0.044715f * x * x * x);
  float e = __expf(2.0f * u);
  return 0.5f * x * (2.0f - 2.0f / (e + 1.0f));
}

// fp32 -> bf16 round-to-nearest-even
__device__ __forceinline__ unsigned short f2bf(float f) {
  union { float f; unsigned u; } v; v.f = f;
  unsigned r = v.u + 0x7FFF + ((v.u >> 16) & 1);
  return (unsigned short)(r >> 16);
}
__device__ __forceinline__ unsigned pack2(float a, float b) {
  return (unsigned)f2bf(a) | ((unsigned)f2bf(b) << 16);
}

// async global->LDS, 16 bytes per lane; LDS dst = wave-uniform base + lane*16
__device__ __forceinline__ void load_lds16(const void* g, void* l) {
  __builtin_amdgcn_global_load_lds(
      (const __attribute__((address_space(1))) void*)g,
      (__attribute__((address_space(3))) void*)l, 16, 0, 0);
}

// ---------------------------------------------------------------------------
// Routing: head = (task-1)&15 for task>0 else invalid. Builds per-head token
// lists; initializes out with b2[h] (stage-2 atomically adds) or 0.
// ---------------------------------------------------------------------------
__global__ __launch_bounds__(256) void route_kernel(
    const int* __restrict__ tasks, const float* __restrict__ b2,
    int* __restrict__ counts, int* __restrict__ lists, float* __restrict__ out) {
  int t = blockIdx.x * 256 + threadIdx.x;
  if (t >= TOK) return;
  int task = tasks[t];
  if (task > 0) {
    int h = (task - 1) & (NH - 1);
    int pos = atomicAdd(&counts[h], 1);
    lists[h * TOK + pos] = t;
    out[t] = b2[h];
  } else {
    out[t] = 0.0f;
  }
}

// ---------------------------------------------------------------------------
// prep_x: X[t][k] = (emb_s[sid]+emb_t[tsk]+v*val_vec)*mask -> bf16 row-major.
// ---------------------------------------------------------------------------
__global__ __launch_bounds__(256) void prep_x(
    const int* __restrict__ selfies, const int* __restrict__ tasks,
    const float* __restrict__ values, const int* __restrict__ pmask,
    const float* __restrict__ emb_s, const float* __restrict__ emb_t,
    const float* __restrict__ val_vec, unsigned short* __restrict__ Xb) {
  int gid = blockIdx.x * 256 + threadIdx.x;   // TOK*128 threads
  int kc = (gid & 127) * 8;
  int t  = gid >> 7;
  int sid = selfies[t], tsk = tasks[t];
  float v = values[t];
  float msk = pmask[t] ? 1.0f : 0.0f;
  const float* ps = emb_s + (size_t)sid * DD + kc;
  const float* pt = emb_t + (size_t)tsk * DD + kc;
  const float* pv = val_vec + kc;
  float r[8];
#pragma unroll
  for (int j = 0; j < 8; j += 4) {
    float4 a = *(const float4*)(ps + j);
    float4 b = *(const float4*)(pt + j);
    float4 c = *(const float4*)(pv + j);
    r[j + 0] = (a.x + b.x + v * c.x) * msk;
    r[j + 1] = (a.y + b.y + v * c.y) * msk;
    r[j + 2] = (a.z + b.z + v * c.z) * msk;
    r[j + 3] = (a.w + b.w + v * c.w) * msk;
  }
  uint4 o;
  o.x = pack2(r[0], r[1]); o.y = pack2(r[2], r[3]);
  o.z = pack2(r[4], r[5]); o.w = pack2(r[6], r[7]);
  *(uint4*)(Xb + (size_t)gid * 8) = o;
}

// ---------------------------------------------------------------------------
// prep_w: transpose+pack Ws and W1 (fp32 k-major) into bf16 MFMA-frag-major:
//   dst[(mat_tile nt)*32 + kc2][lane=q*16+nn][j] = W[kc2*32+q*8+j][nt*16+nn]
// ---------------------------------------------------------------------------
__global__ __launch_bounds__(256) void prep_w(
    const float* __restrict__ Ws, const float* __restrict__ W1,
    unsigned short* __restrict__ Wsp, unsigned short* __restrict__ W1p) {
  int cid = blockIdx.x * 256 + threadIdx.x;
  const float* src;
  unsigned short* dst;
  int stride;
  if (cid < 16 * 128 * 32 * 64) {
    int lane = cid & 63, kc2 = (cid >> 6) & 31, nt = (cid >> 11) & 127, h = cid >> 18;
    src = W1 + ((size_t)h * DD + kc2 * 32 + (lane >> 4) * 8) * FF + nt * 16 + (lane & 15);
    dst = W1p + (size_t)cid * 8;
    stride = FF;
  } else {
    int cid2 = cid - 16 * 128 * 32 * 64;   // < 64*32*64
    int lane = cid2 & 63, kc2 = (cid2 >> 6) & 31, nt = cid2 >> 11;
    src = Ws + ((size_t)kc2 * 32 + (lane >> 4) * 8) * DD + nt * 16 + (lane & 15);
    dst = Wsp + (size_t)cid2 * 8;
    stride = DD;
  }
  float r[8];
#pragma unroll
  for (int j = 0; j < 8; ++j) r[j] = src[(size_t)j * stride];
  uint4 o;
  o.x = pack2(r[0], r[1]); o.y = pack2(r[2], r[3]);
  o.z = pack2(r[4], r[5]); o.w = pack2(r[6], r[7]);
  *(uint4*)dst = o;
}

// ---------------------------------------------------------------------------
// Stage 1: shared = gelu(X @ Ws + bs) in bf16 MFMA. Block = 64m x 128n,
// BK=64, 4 waves, wave = 64m x 32n (4 mt x 2 nt tiles). grid (64, 8).
// PIPELINED: double-buffered LDS, prefetch next K-tile before computing
// current, ONE barrier per K-step (loads drain at the barrier AFTER MFMA).
// ---------------------------------------------------------------------------
__global__ __launch_bounds__(256) void gemm1_mfma(
    const unsigned short* __restrict__ Xb, const unsigned short* __restrict__ Wsp,
    const float* __restrict__ bs, unsigned short* __restrict__ shared_bf) {
  __shared__ __align__(16) unsigned short As[2][2 * 4 * 64 * 8];   // 2 x 8 KB
  __shared__ __align__(16) unsigned short Bs[2][2 * 8 * 64 * 8];   // 2 x 16 KB

  const int tid = threadIdx.x;
  const int lane = tid & 63, w = tid >> 6;
  const int m0 = blockIdx.x * 64;
  const int n0 = blockIdx.y * 128;
  const int q = lane >> 4, c = lane & 15;

  const unsigned short* aSrc = Xb + (size_t)(m0 + w * 16 + c) * DD + q * 8;
  const unsigned short* bBase = Wsp + ((size_t)(blockIdx.y * 8 + w * 2)) * 32 * 512 + lane * 8;
  f32x4 acc[4][2] = {};

  auto stage = [&](int buf, int k0) {
    load_lds16(aSrc + k0,      As[buf] + (size_t)(0 * 256 + w * 64 + lane) * 8);
    load_lds16(aSrc + k0 + 32, As[buf] + (size_t)(1 * 256 + w * 64 + lane) * 8);
    const unsigned short* bk = bBase + k0 * 16;
#pragma unroll
    for (int i = 0; i < 4; ++i) {
      int kk = i >> 1, t = i & 1;
      load_lds16(bk + (size_t)t * 16384 + kk * 512,
                 Bs[buf] + (size_t)(kk * 8 + w * 2 + t) * 512 + lane * 8);
    }
  };
  auto compute = [&](int buf) {
#pragma unroll
    for (int kk = 0; kk < 2; ++kk) {
      bf16x8 a[4], b[2];
#pragma unroll
      for (int mt = 0; mt < 4; ++mt)
        a[mt] = *(const bf16x8*)(As[buf] + (size_t)((kk * 4 + mt) * 64 + lane) * 8);
#pragma unroll
      for (int t = 0; t < 2; ++t)
        b[t] = *(const bf16x8*)(Bs[buf] + (size_t)((kk * 8 + w * 2 + t) * 64 + lane) * 8);
#pragma unroll
      for (int mt = 0; mt < 4; ++mt)
#pragma unroll
        for (int t = 0; t < 2; ++t)
          acc[mt][t] = __builtin_amdgcn_mfma_f32_16x16x32_bf16(a[mt], b[t], acc[mt][t], 0, 0, 0);
    }
  };

  stage(0, 0);
  __syncthreads();
  int cur = 0;
  for (int k0 = 64; k0 < DD; k0 += 64) {
    stage(cur ^ 1, k0);   // issue next-tile loads BEFORE compute
    compute(cur);         // MFMA time covers load latency
    __syncthreads();      // single drain point per K-step
    cur ^= 1;
  }
  compute(cur);

  // Epilogue: +bs, gelu, bf16, scatter u16 stores (C: row=mt*16+q*4+r, col=nt*16+c)
  float bsv[2];
#pragma unroll
  for (int t = 0; t < 2; ++t) bsv[t] = bs[n0 + w * 32 + t * 16 + c];
#pragma unroll
  for (int mt = 0; mt < 4; ++mt)
#pragma unroll
    for (int t = 0; t < 2; ++t)
#pragma unroll
      for (int r = 0; r < 4; ++r) {
        int row = m0 + mt * 16 + q * 4 + r;
        int col = n0 + w * 32 + t * 16 + c;
        shared_bf[(size_t)row * DD + col] = f2bf(gelu_f(acc[mt][t][r] + bsv[t]));
      }
}

// ---------------------------------------------------------------------------
// Stage 2: per-head MLP. Block = 64 tokens x 128 F, BK=64, 4 waves,
// wave = 64m x 32n (4 mt x 2 nt). grid (8 token-tiles, 16 f-chunks, 16 heads)
// -> ~1024 active blocks (~4/CU). Double-buffered LDS (49 KB -> 3 blocks/CU),
// prefetch-before-compute, one barrier per K-step.
// Epilogue: gelu(+b1) dot W2-chunk, shuffle+LDS reduce, atomicAdd into out.
// ---------------------------------------------------------------------------
__global__ __launch_bounds__(256) void gemm2_mfma(
    const unsigned short* __restrict__ shared_bf, const unsigned short* __restrict__ W1p,
    const float* __restrict__ b1, const float* __restrict__ W2,
    const int* __restrict__ counts, const int* __restrict__ lists,
    float* __restrict__ out) {
  const int h = blockIdx.z;
  const int nt_h = counts[h];
  const int m0 = blockIdx.x * 64;
  if (m0 >= nt_h) return;
  const int fc = blockIdx.y;             // f0 = fc*128

  __shared__ __align__(16) unsigned short As[2][2 * 4 * 64 * 8];   // 2 x 8 KB
  __shared__ __align__(16) unsigned short Bs[2][2 * 8 * 64 * 8];   // 2 x 16 KB
  __shared__ int   stok[64];
  __shared__ float red[4][68];

  const int tid = threadIdx.x;
  const int lane = tid & 63, w = tid >> 6;
  const int q = lane >> 4, c = lane & 15;

  if (tid < 64) {
    int i = m0 + tid;
    stok[tid] = (i < nt_h) ? lists[h * TOK + i] : -1;
  }
  __syncthreads();

  // A staging (gathered rows; dead rows read token row 0 -- their accumulator
  // rows are discarded in the epilogue).
  int tokr = stok[w * 16 + c];
  if (tokr < 0) tokr = 0;
  const unsigned short* aSrc = shared_bf + (size_t)tokr * DD + q * 8;

  // B staging: wave w stages nt = fc*8 + w*2 + {0,1}, kk={0,1}
  const unsigned short* bBase =
      W1p + ((size_t)h * 128 + fc * 8 + w * 2) * 32 * 512 + lane * 8;

  f32x4 acc[4][2] = {};

  auto stage = [&](int buf, int k0) {
    load_lds16(aSrc + k0,      As[buf] + (size_t)(0 * 256 + w * 64 + lane) * 8);
    load_lds16(aSrc + k0 + 32, As[buf] + (size_t)(1 * 256 + w * 64 + lane) * 8);
    const unsigned short* bk = bBase + k0 * 16;
#pragma unroll
    for (int i = 0; i < 4; ++i) {
      int kk = i >> 1, t = i & 1;
      load_lds16(bk + (size_t)t * 16384 + kk * 512,
                 Bs[buf] + (size_t)(kk * 8 + w * 2 + t) * 512 + lane * 8);
    }
  };
  auto compute = [&](int buf) {
#pragma unroll
    for (int kk = 0; kk < 2; ++kk) {
      bf16x8 a[4], b[2];
#pragma unroll
      for (int mt = 0; mt < 4; ++mt)
        a[mt] = *(const bf16x8*)(As[buf] + (size_t)((kk * 4 + mt) * 64 + lane) * 8);
#pragma unroll
      for (int t = 0; t < 2; ++t)
        b[t] = *(const bf16x8*)(Bs[buf] + (size_t)((kk * 8 + w * 2 + t) * 64 + lane) * 8);
#pragma unroll
      for (int mt = 0; mt < 4; ++mt)
#pragma unroll
        for (int t = 0; t < 2; ++t)
          acc[mt][t] = __builtin_amdgcn_mfma_f32_16x16x32_bf16(a[mt], b[t], acc[mt][t], 0, 0, 0);
    }
  };

  stage(0, 0);
  __syncthreads();
  int cur = 0;
  for (int k0 = 64; k0 < DD; k0 += 64) {
    stage(cur ^ 1, k0);
    compute(cur);
    __syncthreads();
    cur ^= 1;
  }
  compute(cur);

  // Epilogue: per lane cols n = fc*128 + w*32 + t*16 + c
  const float* b1h = b1 + (size_t)h * FF + fc * 128 + w * 32;
  const float* w2h = W2 + (size_t)h * FF + fc * 128 + w * 32;
  float b1v[2], w2v[2];
#pragma unroll
  for (int t = 0; t < 2; ++t) { b1v[t] = b1h[t * 16 + c]; w2v[t] = w2h[t * 16 + c]; }

#pragma unroll
  for (int mt = 0; mt < 4; ++mt)
#pragma unroll
    for (int r = 0; r < 4; ++r) {
      float s = 0.0f;
#pragma unroll
      for (int t = 0; t < 2; ++t)
        s += gelu_f(acc[mt][t][r] + b1v[t]) * w2v[t];
      s += __shfl_xor(s, 1);
      s += __shfl_xor(s, 2);
      s += __shfl_xor(s, 4);
      s += __shfl_xor(s, 8);
      if (c == 0) red[w][mt * 16 + q * 4 + r] = s;
    }
  __syncthreads();

  if (tid < 64) {
    int t = stok[tid];
    if (t >= 0) {
      float s = red[0][tid] + red[1][tid] + red[2][tid] + red[3][tid];
      atomicAdd(&out[t], s);
    }
  }
}

// ---------------------------------------------------------------------------
extern "C" void kernel_launch(void* const* d_in, const int* in_sizes, int n_in,
                              void* d_out, int out_size, void* d_ws, size_t ws_size,
                              hipStream_t stream) {
  const int*   selfies = (const int*)d_in[0];
  const int*   tasks   = (const int*)d_in[1];
  const float* values  = (const float*)d_in[2];
  const int*   pmask   = (const int*)d_in[3];
  const float* emb_s   = (const float*)d_in[4];
  const float* emb_t   = (const float*)d_in[5];
  const float* val_vec = (const float*)d_in[6];
  const float* Ws      = (const float*)d_in[7];
  const float* bs      = (const float*)d_in[8];
  const float* W1      = (const float*)d_in[9];
  const float* b1      = (const float*)d_in[10];
  const float* W2      = (const float*)d_in[11];
  const float* b2      = (const float*)d_in[12];
  float* out = (float*)d_out;

  // Workspace layout (all 256-B aligned):
  //   Xb        bf16 [4096][1024]            8 MB
  //   shared_bf bf16 [4096][1024]            8 MB
  //   Wsp       bf16 frag-major              2 MB
  //   W1p       bf16 frag-major             64 MB
  //   counts    int[16] ; lists int[16*4096]
  char* ws = (char*)d_ws;
  unsigned short* Xb        = (unsigned short*)ws;
  unsigned short* shared_bf = (unsigned short*)(ws + (8u << 20));
  unsigned short* Wsp       = (unsigned short*)(ws + (16u << 20));
  unsigned short* W1p       = (unsigned short*)(ws + (18u << 20));
  int* counts = (int*)(ws + (82u << 20));
  int* lists  = (int*)(ws + (82u << 20) + 256);

  hipMemsetAsync(counts, 0, NH * sizeof(int), stream);
  route_kernel<<<TOK / 256, 256, 0, stream>>>(tasks, b2, counts, lists, out);
  prep_x<<<TOK * 128 / 256, 256, 0, stream>>>(selfies, tasks, values, pmask,
                                              emb_s, emb_t, val_vec, Xb);
  prep_w<<<(16 * 128 * 32 * 64 + 64 * 32 * 64) / 256, 256, 0, stream>>>(Ws, W1, Wsp, W1p);
  gemm1_mfma<<<dim3(TOK / 64, DD / 128), 256, 0, stream>>>(Xb, Wsp, bs, shared_bf);
  gemm2_mfma<<<dim3(8, FF / 128, NH), 256, 0, stream>>>(shared_bf, W1p, b1, W2,
                                                        counts, lists, out);
}

// Round 2
// 320.206 us; speedup vs baseline: 1.1206x; 1.1206x over previous
//
#include <hip/hip_runtime.h>
#include <hip/hip_bf16.h>

// B=8, S=512 -> TOK=4096 tokens, D=1024, F=2048, H=16 heads, O=1.
#define TOK 4096
#define DD  1024
#define FF  2048
#define NH  16

typedef short bf16x8 __attribute__((ext_vector_type(8)));
typedef float f32x4  __attribute__((ext_vector_type(4)));

__device__ __forceinline__ float gelu_f(float x) {
  float u = 0.7978845608028654f * (x + 0.044715f * x * x * x);
  float e = __expf(2.0f * u);
  return 0.5f * x * (2.0f - 2.0f / (e + 1.0f));
}

// fp32 -> bf16 round-to-nearest-even
__device__ __forceinline__ unsigned short f2bf(float f) {
  union { float f; unsigned u; } v; v.f = f;
  unsigned r = v.u + 0x7FFF + ((v.u >> 16) & 1);
  return (unsigned short)(r >> 16);
}
__device__ __forceinline__ unsigned pack2(float a, float b) {
  return (unsigned)f2bf(a) | ((unsigned)f2bf(b) << 16);
}

// async global->LDS, 16 bytes per lane; LDS dst = wave-uniform base + lane*16
__device__ __forceinline__ void load_lds16(const void* g, void* l) {
  __builtin_amdgcn_global_load_lds(
      (const __attribute__((address_space(1))) void*)g,
      (__attribute__((address_space(3))) void*)l, 16, 0, 0);
}

// ---------------------------------------------------------------------------
// Routing: head = (task-1)&15 for task>0 else invalid. Builds per-head token
// lists; initializes out with b2[h] (stage-2 atomically adds) or 0.
// ---------------------------------------------------------------------------
__global__ __launch_bounds__(256) void route_kernel(
    const int* __restrict__ tasks, const float* __restrict__ b2,
    int* __restrict__ counts, int* __restrict__ lists, float* __restrict__ out) {
  int t = blockIdx.x * 256 + threadIdx.x;
  if (t >= TOK) return;
  int task = tasks[t];
  if (task > 0) {
    int h = (task - 1) & (NH - 1);
    int pos = atomicAdd(&counts[h], 1);
    lists[h * TOK + pos] = t;
    out[t] = b2[h];
  } else {
    out[t] = 0.0f;
  }
}

// ---------------------------------------------------------------------------
// prep_x: X[t][k] = (emb_s[sid]+emb_t[tsk]+v*val_vec)*mask -> bf16 row-major.
// ---------------------------------------------------------------------------
__global__ __launch_bounds__(256) void prep_x(
    const int* __restrict__ selfies, const int* __restrict__ tasks,
    const float* __restrict__ values, const int* __restrict__ pmask,
    const float* __restrict__ emb_s, const float* __restrict__ emb_t,
    const float* __restrict__ val_vec, unsigned short* __restrict__ Xb) {
  int gid = blockIdx.x * 256 + threadIdx.x;   // TOK*128 threads
  int kc = (gid & 127) * 8;
  int t  = gid >> 7;
  int sid = selfies[t], tsk = tasks[t];
  float v = values[t];
  float msk = pmask[t] ? 1.0f : 0.0f;
  const float* ps = emb_s + (size_t)sid * DD + kc;
  const float* pt = emb_t + (size_t)tsk * DD + kc;
  const float* pv = val_vec + kc;
  float r[8];
#pragma unroll
  for (int j = 0; j < 8; j += 4) {
    float4 a = *(const float4*)(ps + j);
    float4 b = *(const float4*)(pt + j);
    float4 c = *(const float4*)(pv + j);
    r[j + 0] = (a.x + b.x + v * c.x) * msk;
    r[j + 1] = (a.y + b.y + v * c.y) * msk;
    r[j + 2] = (a.z + b.z + v * c.z) * msk;
    r[j + 3] = (a.w + b.w + v * c.w) * msk;
  }
  uint4 o;
  o.x = pack2(r[0], r[1]); o.y = pack2(r[2], r[3]);
  o.z = pack2(r[4], r[5]); o.w = pack2(r[6], r[7]);
  *(uint4*)(Xb + (size_t)gid * 8) = o;
}

// ---------------------------------------------------------------------------
// prep_w: transpose+pack Ws and W1 (fp32 k-major) into bf16 MFMA-frag-major.
// REWRITE: coalesced 64k x 64f tile read -> LDS -> transposed frag-major
// stores. Replaces the old 8-KB-strided fp32 reads.
// Frag layout (unchanged): chunk = (nt_g*32 + kc2)*64 + lane holds 8 elems,
//   elem j = W[kc2*32 + (lane>>4)*8 + j][nt*16 + (lane&15)].
// ---------------------------------------------------------------------------
#define W1_TILES (16 * 16 * 32)   // h x kb(16) x fb(32)
#define WS_TILES (16 * 16)        // kb(16) x fb(16)

__global__ __launch_bounds__(256) void prep_w(
    const float* __restrict__ Ws, const float* __restrict__ W1,
    unsigned short* __restrict__ Wsp, unsigned short* __restrict__ W1p) {
  __shared__ unsigned short T[64][70];   // pad 70: phase-2 col reads ~conflict-free
  int bid = blockIdx.x;
  const float* src; unsigned short* dstBase; int stride, nt0, kc0;
  if (bid < W1_TILES) {
    int fb = bid & 31, kb = (bid >> 5) & 15, h = bid >> 9;
    src = W1 + ((size_t)h * DD + kb * 64) * FF + fb * 64;
    stride = FF;
    nt0 = h * 128 + fb * 4;          // global nt index (incl. head offset)
    kc0 = kb * 2;
    dstBase = W1p;
  } else {
    int b2 = bid - W1_TILES;
    int fb = b2 & 15, kb = b2 >> 4;
    src = Ws + (size_t)(kb * 64) * DD + fb * 64;
    stride = DD;
    nt0 = fb * 4;
    kc0 = kb * 2;
    dstBase = Wsp;
  }
  const int tid = threadIdx.x;
  // Phase 1: coalesced read of 64 rows x 64 cols fp32; row r = tid>>2,
  // cols (tid&3)*16 .. +15 (64B contiguous per thread across 4 float4s).
  {
    int r = tid >> 2, cq = (tid & 3) * 16;
    const float* p = src + (size_t)r * stride + cq;
#pragma unroll
    for (int i = 0; i < 4; ++i) {
      float4 v = *(const float4*)(p + i * 4);
      *(unsigned*)&T[r][cq + i * 4 + 0] = pack2(v.x, v.y);
      *(unsigned*)&T[r][cq + i * 4 + 2] = pack2(v.z, v.w);
    }
  }
  __syncthreads();
  // Phase 2: each thread emits 2 frag chunks (16B, coalesced stores).
#pragma unroll
  for (int cc = 0; cc < 2; ++cc) {
    int idx = tid + cc * 256;                 // (ntl*2 + kcl)*64 + lane
    int lane2 = idx & 63, kcl = (idx >> 6) & 1, ntl = idx >> 7;
    int n_local = ntl * 16 + (lane2 & 15);
    int r0 = kcl * 32 + (lane2 >> 4) * 8;
    unsigned short e[8];
#pragma unroll
    for (int j = 0; j < 8; ++j) e[j] = T[r0 + j][n_local];
    uint4 o;
    o.x = (unsigned)e[0] | ((unsigned)e[1] << 16);
    o.y = (unsigned)e[2] | ((unsigned)e[3] << 16);
    o.z = (unsigned)e[4] | ((unsigned)e[5] << 16);
    o.w = (unsigned)e[6] | ((unsigned)e[7] << 16);
    size_t chunk = ((size_t)(nt0 + ntl) * 32 + (kc0 + kcl)) * 64 + lane2;
    *(uint4*)(dstBase + chunk * 8) = o;
  }
}

// ---------------------------------------------------------------------------
// Stage 1: shared = gelu(X @ Ws + bs) in bf16 MFMA. Block = 64m x 128n,
// BK=64, 4 waves, wave = 64m x 32n. grid (64, 8).
// T4 pipeline: double-buffered LDS, counted s_waitcnt vmcnt(6) + raw
// s_barrier -- prefetch loads stay in flight ACROSS the barrier (never
// drained to 0 in the main loop). 6 global_load_lds per wave per stage;
// all other VMEM loads pinned before the first stage.
// ---------------------------------------------------------------------------
__global__ __launch_bounds__(256) void gemm1_mfma(
    const unsigned short* __restrict__ Xb, const unsigned short* __restrict__ Wsp,
    const float* __restrict__ bs, unsigned short* __restrict__ shared_bf) {
  __shared__ __align__(16) unsigned short As[2][2 * 4 * 64 * 8];   // 2 x 8 KB
  __shared__ __align__(16) unsigned short Bs[2][2 * 8 * 64 * 8];   // 2 x 16 KB

  const int tid = threadIdx.x;
  const int lane = tid & 63, w = tid >> 6;
  const int m0 = blockIdx.x * 64;
  const int n0 = blockIdx.y * 128;
  const int q = lane >> 4, c = lane & 15;

  const unsigned short* aSrc = Xb + (size_t)(m0 + w * 16 + c) * DD + q * 8;
  const unsigned short* bBase = Wsp + ((size_t)(blockIdx.y * 8 + w * 2)) * 32 * 512 + lane * 8;
  f32x4 acc[4][2] = {};

  // Pin epilogue loads BEFORE first stage so the vmcnt count stays exact.
  float bsv[2];
  bsv[0] = bs[n0 + w * 32 + c];
  bsv[1] = bs[n0 + w * 32 + 16 + c];
  asm volatile("" :: "v"(bsv[0]), "v"(bsv[1]));

  auto stage = [&](int buf, int k0) {
    load_lds16(aSrc + k0,      As[buf] + (size_t)(0 * 256 + w * 64 + lane) * 8);
    load_lds16(aSrc + k0 + 32, As[buf] + (size_t)(1 * 256 + w * 64 + lane) * 8);
    const unsigned short* bk = bBase + k0 * 16;
#pragma unroll
    for (int i = 0; i < 4; ++i) {
      int kk = i >> 1, t = i & 1;
      load_lds16(bk + (size_t)t * 16384 + kk * 512,
                 Bs[buf] + (size_t)(kk * 8 + w * 2 + t) * 512 + lane * 8);
    }
  };
  auto compute = [&](int buf) {
#pragma unroll
    for (int kk = 0; kk < 2; ++kk) {
      bf16x8 a[4], b[2];
#pragma unroll
      for (int mt = 0; mt < 4; ++mt)
        a[mt] = *(const bf16x8*)(As[buf] + (size_t)((kk * 4 + mt) * 64 + lane) * 8);
#pragma unroll
      for (int t = 0; t < 2; ++t)
        b[t] = *(const bf16x8*)(Bs[buf] + (size_t)((kk * 8 + w * 2 + t) * 64 + lane) * 8);
#pragma unroll
      for (int mt = 0; mt < 4; ++mt)
#pragma unroll
        for (int t = 0; t < 2; ++t)
          acc[mt][t] = __builtin_amdgcn_mfma_f32_16x16x32_bf16(a[mt], b[t], acc[mt][t], 0, 0, 0);
    }
  };

  stage(0, 0);
  stage(1, 64);
  asm volatile("s_waitcnt vmcnt(6)" ::: "memory");
  __builtin_amdgcn_s_barrier();
  int cur = 0;
  for (int i = 0; i < 14; ++i) {
    compute(cur);                         // reads buf cur (tile i)
    asm volatile("" ::: "memory");
    __builtin_amdgcn_s_barrier();         // all waves done reading buf cur
    stage(cur, (i + 2) * 64);             // tile i+2 -> buf cur
    asm volatile("s_waitcnt vmcnt(6)" ::: "memory");  // tile i+1 landed
    __builtin_amdgcn_s_barrier();
    cur ^= 1;
  }
  compute(cur);                           // tile 14
  asm volatile("s_waitcnt vmcnt(0)" ::: "memory");
  __builtin_amdgcn_s_barrier();
  compute(cur ^ 1);                       // tile 15

  // Epilogue: +bs, gelu, bf16, scatter u16 stores
#pragma unroll
  for (int mt = 0; mt < 4; ++mt)
#pragma unroll
    for (int t = 0; t < 2; ++t)
#pragma unroll
      for (int r = 0; r < 4; ++r) {
        int row = m0 + mt * 16 + q * 4 + r;
        int col = n0 + w * 32 + t * 16 + c;
        shared_bf[(size_t)row * DD + col] = f2bf(gelu_f(acc[mt][t][r] + bsv[t]));
      }
}

// ---------------------------------------------------------------------------
// Stage 2: per-head MLP. Block = 64 tokens x 128 F, BK=64, 4 waves.
// 1-D grid 2048, decoded so each head's blocks land on ONE XCD (assumes
// XCD = blockIdx % 8 round-robin): head slice of W1p = 4 MB = one XCD L2.
// Same T4 counted-vmcnt pipeline as gemm1.
// ---------------------------------------------------------------------------
__global__ __launch_bounds__(256) void gemm2_mfma(
    const unsigned short* __restrict__ shared_bf, const unsigned short* __restrict__ W1p,
    const float* __restrict__ b1, const float* __restrict__ W2,
    const int* __restrict__ counts, const int* __restrict__ lists,
    float* __restrict__ out) {
  // XCD-pinned decode: xcd = id&7 -> heads {xcd, xcd+8}; h outermost within
  // xcd so one head's 4 MB W1p slice stays L2-resident across its m-rounds.
  const int id = blockIdx.x;
  const int xcd = id & 7, local_ = id >> 3;       // local 0..255
  const int h = xcd + 8 * (local_ >> 7);
  const int rest = local_ & 127;
  const int fc = rest & 15;                       // f0 = fc*128
  const int m0 = (rest >> 4) * 64;
  const int nt_h = counts[h];
  if (m0 >= nt_h) return;

  __shared__ __align__(16) unsigned short As[2][2 * 4 * 64 * 8];   // 2 x 8 KB
  __shared__ __align__(16) unsigned short Bs[2][2 * 8 * 64 * 8];   // 2 x 16 KB
  __shared__ int   stok[64];
  __shared__ float red[4][68];

  const int tid = threadIdx.x;
  const int lane = tid & 63, w = tid >> 6;
  const int q = lane >> 4, c = lane & 15;

  if (tid < 64) {
    int i = m0 + tid;
    stok[tid] = (i < nt_h) ? lists[h * TOK + i] : -1;
  }
  __syncthreads();   // full drain: stok loads complete before pipeline starts

  int tokr = stok[w * 16 + c];
  if (tokr < 0) tokr = 0;
  const unsigned short* aSrc = shared_bf + (size_t)tokr * DD + q * 8;
  const unsigned short* bBase =
      W1p + ((size_t)h * 128 + fc * 8 + w * 2) * 32 * 512 + lane * 8;

  f32x4 acc[4][2] = {};

  // Pin epilogue loads BEFORE first stage (keeps vmcnt count exact).
  const float* b1h = b1 + (size_t)h * FF + fc * 128 + w * 32;
  const float* w2h = W2 + (size_t)h * FF + fc * 128 + w * 32;
  float b1v[2], w2v[2];
  b1v[0] = b1h[c];      b1v[1] = b1h[16 + c];
  w2v[0] = w2h[c];      w2v[1] = w2h[16 + c];
  asm volatile("" :: "v"(b1v[0]), "v"(b1v[1]), "v"(w2v[0]), "v"(w2v[1]));

  auto stage = [&](int buf, int k0) {
    load_lds16(aSrc + k0,      As[buf] + (size_t)(0 * 256 + w * 64 + lane) * 8);
    load_lds16(aSrc + k0 + 32, As[buf] + (size_t)(1 * 256 + w * 64 + lane) * 8);
    const unsigned short* bk = bBase + k0 * 16;
#pragma unroll
    for (int i = 0; i < 4; ++i) {
      int kk = i >> 1, t = i & 1;
      load_lds16(bk + (size_t)t * 16384 + kk * 512,
                 Bs[buf] + (size_t)(kk * 8 + w * 2 + t) * 512 + lane * 8);
    }
  };
  auto compute = [&](int buf) {
#pragma unroll
    for (int kk = 0; kk < 2; ++kk) {
      bf16x8 a[4], b[2];
#pragma unroll
      for (int mt = 0; mt < 4; ++mt)
        a[mt] = *(const bf16x8*)(As[buf] + (size_t)((kk * 4 + mt) * 64 + lane) * 8);
#pragma unroll
      for (int t = 0; t < 2; ++t)
        b[t] = *(const bf16x8*)(Bs[buf] + (size_t)((kk * 8 + w * 2 + t) * 64 + lane) * 8);
#pragma unroll
      for (int mt = 0; mt < 4; ++mt)
#pragma unroll
        for (int t = 0; t < 2; ++t)
          acc[mt][t] = __builtin_amdgcn_mfma_f32_16x16x32_bf16(a[mt], b[t], acc[mt][t], 0, 0, 0);
    }
  };

  stage(0, 0);
  stage(1, 64);
  asm volatile("s_waitcnt vmcnt(6)" ::: "memory");
  __builtin_amdgcn_s_barrier();
  int cur = 0;
  for (int i = 0; i < 14; ++i) {
    compute(cur);
    asm volatile("" ::: "memory");
    __builtin_amdgcn_s_barrier();
    stage(cur, (i + 2) * 64);
    asm volatile("s_waitcnt vmcnt(6)" ::: "memory");
    __builtin_amdgcn_s_barrier();
    cur ^= 1;
  }
  compute(cur);
  asm volatile("s_waitcnt vmcnt(0)" ::: "memory");
  __builtin_amdgcn_s_barrier();
  compute(cur ^ 1);

  // Epilogue: per lane cols n = fc*128 + w*32 + t*16 + c
#pragma unroll
  for (int mt = 0; mt < 4; ++mt)
#pragma unroll
    for (int r = 0; r < 4; ++r) {
      float s = 0.0f;
#pragma unroll
      for (int t = 0; t < 2; ++t)
        s += gelu_f(acc[mt][t][r] + b1v[t]) * w2v[t];
      s += __shfl_xor(s, 1);
      s += __shfl_xor(s, 2);
      s += __shfl_xor(s, 4);
      s += __shfl_xor(s, 8);
      if (c == 0) red[w][mt * 16 + q * 4 + r] = s;
    }
  __syncthreads();

  if (tid < 64) {
    int t = stok[tid];
    if (t >= 0) {
      float s = red[0][tid] + red[1][tid] + red[2][tid] + red[3][tid];
      atomicAdd(&out[t], s);
    }
  }
}

// ---------------------------------------------------------------------------
extern "C" void kernel_launch(void* const* d_in, const int* in_sizes, int n_in,
                              void* d_out, int out_size, void* d_ws, size_t ws_size,
                              hipStream_t stream) {
  const int*   selfies = (const int*)d_in[0];
  const int*   tasks   = (const int*)d_in[1];
  const float* values  = (const float*)d_in[2];
  const int*   pmask   = (const int*)d_in[3];
  const float* emb_s   = (const float*)d_in[4];
  const float* emb_t   = (const float*)d_in[5];
  const float* val_vec = (const float*)d_in[6];
  const float* Ws      = (const float*)d_in[7];
  const float* bs      = (const float*)d_in[8];
  const float* W1      = (const float*)d_in[9];
  const float* b1      = (const float*)d_in[10];
  const float* W2      = (const float*)d_in[11];
  const float* b2      = (const float*)d_in[12];
  float* out = (float*)d_out;

  // Workspace layout (all 256-B aligned):
  //   Xb        bf16 [4096][1024]            8 MB
  //   shared_bf bf16 [4096][1024]            8 MB
  //   Wsp       bf16 frag-major              2 MB
  //   W1p       bf16 frag-major             64 MB
  //   counts    int[16] ; lists int[16*4096]
  char* ws = (char*)d_ws;
  unsigned short* Xb        = (unsigned short*)ws;
  unsigned short* shared_bf = (unsigned short*)(ws + (8u << 20));
  unsigned short* Wsp       = (unsigned short*)(ws + (16u << 20));
  unsigned short* W1p       = (unsigned short*)(ws + (18u << 20));
  int* counts = (int*)(ws + (82u << 20));
  int* lists  = (int*)(ws + (82u << 20) + 256);

  hipMemsetAsync(counts, 0, NH * sizeof(int), stream);
  route_kernel<<<TOK / 256, 256, 0, stream>>>(tasks, b2, counts, lists, out);
  prep_x<<<TOK * 128 / 256, 256, 0, stream>>>(selfies, tasks, values, pmask,
                                              emb_s, emb_t, val_vec, Xb);
  prep_w<<<W1_TILES + WS_TILES, 256, 0, stream>>>(Ws, W1, Wsp, W1p);
  gemm1_mfma<<<dim3(TOK / 64, DD / 128), 256, 0, stream>>>(Xb, Wsp, bs, shared_bf);
  gemm2_mfma<<<2048, 256, 0, stream>>>(shared_bf, W1p, b1, W2,
                                       counts, lists, out);
}

// Round 3
// 304.193 us; speedup vs baseline: 1.1796x; 1.0526x over previous
//
#include <hip/hip_runtime.h>
#include <hip/hip_bf16.h>

// B=8, S=512 -> TOK=4096 tokens, D=1024, F=2048, H=16 heads, O=1.
#define TOK 4096
#define DD  1024
#define FF  2048
#define NH  16

typedef short bf16x8 __attribute__((ext_vector_type(8)));
typedef float f32x4  __attribute__((ext_vector_type(4)));

__device__ __forceinline__ float gelu_f(float x) {
  float u = 0.7978845608028654f * (x + 0.044715f * x * x * x);
  float e = __expf(2.0f * u);
  return 0.5f * x * (2.0f - 2.0f / (e + 1.0f));
}

// fp32 -> bf16 round-to-nearest-even
__device__ __forceinline__ unsigned short f2bf(float f) {
  union { float f; unsigned u; } v; v.f = f;
  unsigned r = v.u + 0x7FFF + ((v.u >> 16) & 1);
  return (unsigned short)(r >> 16);
}
__device__ __forceinline__ unsigned pack2(float a, float b) {
  return (unsigned)f2bf(a) | ((unsigned)f2bf(b) << 16);
}

// async global->LDS, 16 bytes per lane; LDS dst = wave-uniform base + lane*16
__device__ __forceinline__ void load_lds16(const void* g, void* l) {
  __builtin_amdgcn_global_load_lds(
      (const __attribute__((address_space(1))) void*)g,
      (__attribute__((address_space(3))) void*)l, 16, 0, 0);
}

// ---------------------------------------------------------------------------
// Fused preprocessing: one launch covers prep_w tiles, prep_x chunks and
// routing. All parts write disjoint memory; counts pre-zeroed by memset.
// ---------------------------------------------------------------------------
#define W1_TILES (16 * 16 * 32)   // h x kb(16) x fb(32)
#define WS_TILES (16 * 16)        // kb(16) x fb(16)
#define PW_BLKS  (W1_TILES + WS_TILES)   // 8448
#define PX_BLKS  (TOK * 128 / 256)       // 2048

__device__ void prep_w_body(
    int bid, const float* __restrict__ Ws, const float* __restrict__ W1,
    unsigned short* __restrict__ Wsp, unsigned short* __restrict__ W1p) {
  __shared__ unsigned short T[64][70];   // pad 70: phase-2 col reads ~conflict-free
  const float* src; unsigned short* dstBase; int stride, nt0, kc0;
  if (bid < W1_TILES) {
    int fb = bid & 31, kb = (bid >> 5) & 15, h = bid >> 9;
    src = W1 + ((size_t)h * DD + kb * 64) * FF + fb * 64;
    stride = FF;
    nt0 = h * 128 + fb * 4;          // global nt index (incl. head offset)
    kc0 = kb * 2;
    dstBase = W1p;
  } else {
    int b2 = bid - W1_TILES;
    int fb = b2 & 15, kb = b2 >> 4;
    src = Ws + (size_t)(kb * 64) * DD + fb * 64;
    stride = DD;
    nt0 = fb * 4;
    kc0 = kb * 2;
    dstBase = Wsp;
  }
  const int tid = threadIdx.x;
  // Phase 1: coalesced read of 64 rows x 64 cols fp32.
  {
    int r = tid >> 2, cq = (tid & 3) * 16;
    const float* p = src + (size_t)r * stride + cq;
#pragma unroll
    for (int i = 0; i < 4; ++i) {
      float4 v = *(const float4*)(p + i * 4);
      *(unsigned*)&T[r][cq + i * 4 + 0] = pack2(v.x, v.y);
      *(unsigned*)&T[r][cq + i * 4 + 2] = pack2(v.z, v.w);
    }
  }
  __syncthreads();
  // Phase 2: each thread emits 2 frag chunks (16B, coalesced stores).
#pragma unroll
  for (int cc = 0; cc < 2; ++cc) {
    int idx = tid + cc * 256;                 // (ntl*2 + kcl)*64 + lane
    int lane2 = idx & 63, kcl = (idx >> 6) & 1, ntl = idx >> 7;
    int n_local = ntl * 16 + (lane2 & 15);
    int r0 = kcl * 32 + (lane2 >> 4) * 8;
    unsigned short e[8];
#pragma unroll
    for (int j = 0; j < 8; ++j) e[j] = T[r0 + j][n_local];
    uint4 o;
    o.x = (unsigned)e[0] | ((unsigned)e[1] << 16);
    o.y = (unsigned)e[2] | ((unsigned)e[3] << 16);
    o.z = (unsigned)e[4] | ((unsigned)e[5] << 16);
    o.w = (unsigned)e[6] | ((unsigned)e[7] << 16);
    size_t chunk = ((size_t)(nt0 + ntl) * 32 + (kc0 + kcl)) * 64 + lane2;
    *(uint4*)(dstBase + chunk * 8) = o;
  }
}

__device__ void prep_x_body(
    int gid, const int* __restrict__ selfies, const int* __restrict__ tasks,
    const float* __restrict__ values, const int* __restrict__ pmask,
    const float* __restrict__ emb_s, const float* __restrict__ emb_t,
    const float* __restrict__ val_vec, unsigned short* __restrict__ Xb) {
  int kc = (gid & 127) * 8;
  int t  = gid >> 7;
  int sid = selfies[t], tsk = tasks[t];
  float v = values[t];
  float msk = pmask[t] ? 1.0f : 0.0f;
  const float* ps = emb_s + (size_t)sid * DD + kc;
  const float* pt = emb_t + (size_t)tsk * DD + kc;
  const float* pv = val_vec + kc;
  float r[8];
#pragma unroll
  for (int j = 0; j < 8; j += 4) {
    float4 a = *(const float4*)(ps + j);
    float4 b = *(const float4*)(pt + j);
    float4 c = *(const float4*)(pv + j);
    r[j + 0] = (a.x + b.x + v * c.x) * msk;
    r[j + 1] = (a.y + b.y + v * c.y) * msk;
    r[j + 2] = (a.z + b.z + v * c.z) * msk;
    r[j + 3] = (a.w + b.w + v * c.w) * msk;
  }
  uint4 o;
  o.x = pack2(r[0], r[1]); o.y = pack2(r[2], r[3]);
  o.z = pack2(r[4], r[5]); o.w = pack2(r[6], r[7]);
  *(uint4*)(Xb + (size_t)gid * 8) = o;
}

__global__ __launch_bounds__(256) void prep_all(
    const int* __restrict__ selfies, const int* __restrict__ tasks,
    const float* __restrict__ values, const int* __restrict__ pmask,
    const float* __restrict__ emb_s, const float* __restrict__ emb_t,
    const float* __restrict__ val_vec, const float* __restrict__ Ws,
    const float* __restrict__ W1, const float* __restrict__ b2,
    unsigned short* __restrict__ Xb, unsigned short* __restrict__ Wsp,
    unsigned short* __restrict__ W1p,
    int* __restrict__ counts, int* __restrict__ lists, float* __restrict__ out) {
  int bid = blockIdx.x;
  if (bid < PW_BLKS) {
    prep_w_body(bid, Ws, W1, Wsp, W1p);
  } else if (bid < PW_BLKS + PX_BLKS) {
    prep_x_body((bid - PW_BLKS) * 256 + threadIdx.x,
                selfies, tasks, values, pmask, emb_s, emb_t, val_vec, Xb);
  } else {
    int t = (bid - PW_BLKS - PX_BLKS) * 256 + threadIdx.x;
    if (t < TOK) {
      int task = tasks[t];
      if (task > 0) {
        int h = (task - 1) & (NH - 1);
        int pos = atomicAdd(&counts[h], 1);
        lists[h * TOK + pos] = t;
        out[t] = b2[h];
      } else {
        out[t] = 0.0f;
      }
    }
  }
}

// ---------------------------------------------------------------------------
// Stage 1: shared = gelu(X @ Ws + bs). Block = 64m x 128n, BK=32, 4 waves.
// QUAD-buffered LDS (48 KB -> 3 blocks/CU), 2-deep prefetch with counted
// s_waitcnt vmcnt(6), ONE s_barrier per K-step (buffer-reuse distance = 3
// barriers with 4 buffers, so a single collective barrier both publishes
// tile i and retires the oldest buffer). 3 loads/wave/stage.
// ---------------------------------------------------------------------------
__global__ __launch_bounds__(256) void gemm1_mfma(
    const unsigned short* __restrict__ Xb, const unsigned short* __restrict__ Wsp,
    const float* __restrict__ bs, unsigned short* __restrict__ shared_bf) {
  __shared__ __align__(16) unsigned short As[4][4 * 64 * 8];   // 4 x 4 KB
  __shared__ __align__(16) unsigned short Bs[4][8 * 64 * 8];   // 4 x 8 KB

  const int tid = threadIdx.x;
  const int lane = tid & 63, w = tid >> 6;
  const int m0 = blockIdx.x * 64;
  const int n0 = blockIdx.y * 128;
  const int q = lane >> 4, c = lane & 15;

  const unsigned short* aSrc = Xb + (size_t)(m0 + w * 16 + c) * DD + q * 8;
  const unsigned short* bBase = Wsp + ((size_t)(blockIdx.y * 8 + w * 2)) * 32 * 512 + lane * 8;
  f32x4 acc[4][2] = {};

  // Pin epilogue loads BEFORE first stage so the vmcnt count stays exact.
  float bsv[2];
  bsv[0] = bs[n0 + w * 32 + c];
  bsv[1] = bs[n0 + w * 32 + 16 + c];
  asm volatile("" :: "v"(bsv[0]), "v"(bsv[1]));

  auto stage = [&](int buf, int kc2) {           // kc2 = K-step (32 k)
    load_lds16(aSrc + kc2 * 32, As[buf] + (size_t)(w * 64 + lane) * 8);
    const unsigned short* bk = bBase + kc2 * 512;
    load_lds16(bk,            Bs[buf] + (size_t)((w * 2 + 0) * 64 + lane) * 8);
    load_lds16(bk + 16384,    Bs[buf] + (size_t)((w * 2 + 1) * 64 + lane) * 8);
  };
  auto compute = [&](int buf) {
    bf16x8 a[4], b[2];
#pragma unroll
    for (int mt = 0; mt < 4; ++mt)
      a[mt] = *(const bf16x8*)(As[buf] + (size_t)(mt * 64 + lane) * 8);
#pragma unroll
    for (int t = 0; t < 2; ++t)
      b[t] = *(const bf16x8*)(Bs[buf] + (size_t)((w * 2 + t) * 64 + lane) * 8);
    __builtin_amdgcn_s_setprio(1);
#pragma unroll
    for (int mt = 0; mt < 4; ++mt)
#pragma unroll
      for (int t = 0; t < 2; ++t)
        acc[mt][t] = __builtin_amdgcn_mfma_f32_16x16x32_bf16(a[mt], b[t], acc[mt][t], 0, 0, 0);
    __builtin_amdgcn_s_setprio(0);
  };

  stage(0, 0);
  stage(1, 1);
  for (int i = 0; i < 30; ++i) {
    stage((i + 2) & 3, i + 2);                      // 2-deep prefetch
    asm volatile("s_waitcnt vmcnt(6)" ::: "memory"); // tile i landed
    __builtin_amdgcn_s_barrier();                    // publish i / retire oldest
    compute(i & 3);
    asm volatile("" ::: "memory");
  }
  asm volatile("s_waitcnt vmcnt(3)" ::: "memory");
  __builtin_amdgcn_s_barrier();
  compute(2);                                        // tile 30
  asm volatile("" ::: "memory");
  asm volatile("s_waitcnt vmcnt(0)" ::: "memory");
  __builtin_amdgcn_s_barrier();
  compute(3);                                        // tile 31

  // Epilogue: +bs, gelu, bf16, scatter u16 stores
#pragma unroll
  for (int mt = 0; mt < 4; ++mt)
#pragma unroll
    for (int t = 0; t < 2; ++t)
#pragma unroll
      for (int r = 0; r < 4; ++r) {
        int row = m0 + mt * 16 + q * 4 + r;
        int col = n0 + w * 32 + t * 16 + c;
        shared_bf[(size_t)row * DD + col] = f2bf(gelu_f(acc[mt][t][r] + bsv[t]));
      }
}

// ---------------------------------------------------------------------------
// Stage 2: per-head MLP. Block = 64 tokens x 128 F, BK=32, 4 waves.
// XCD-pinned 1-D grid 2048 (xcd = id&7 -> heads {xcd, xcd+8}); same
// quad-buffer / one-barrier / vmcnt(6) pipeline as gemm1.
// ---------------------------------------------------------------------------
__global__ __launch_bounds__(256) void gemm2_mfma(
    const unsigned short* __restrict__ shared_bf, const unsigned short* __restrict__ W1p,
    const float* __restrict__ b1, const float* __restrict__ W2,
    const int* __restrict__ counts, const int* __restrict__ lists,
    float* __restrict__ out) {
  const int id = blockIdx.x;
  const int xcd = id & 7, local_ = id >> 3;       // local 0..255
  const int h = xcd + 8 * (local_ >> 7);
  const int rest = local_ & 127;
  const int fc = rest & 15;                       // f0 = fc*128
  const int m0 = (rest >> 4) * 64;
  const int nt_h = counts[h];
  if (m0 >= nt_h) return;

  __shared__ __align__(16) unsigned short As[4][4 * 64 * 8];   // 4 x 4 KB
  __shared__ __align__(16) unsigned short Bs[4][8 * 64 * 8];   // 4 x 8 KB
  __shared__ int   stok[64];
  __shared__ float red[4][68];

  const int tid = threadIdx.x;
  const int lane = tid & 63, w = tid >> 6;
  const int q = lane >> 4, c = lane & 15;

  if (tid < 64) {
    int i = m0 + tid;
    stok[tid] = (i < nt_h) ? lists[h * TOK + i] : -1;
  }
  __syncthreads();   // full drain: stok loads complete before pipeline starts

  int tokr = stok[w * 16 + c];
  if (tokr < 0) tokr = 0;
  const unsigned short* aSrc = shared_bf + (size_t)tokr * DD + q * 8;
  const unsigned short* bBase =
      W1p + ((size_t)h * 128 + fc * 8 + w * 2) * 32 * 512 + lane * 8;

  f32x4 acc[4][2] = {};

  // Pin epilogue loads BEFORE first stage (keeps vmcnt count exact).
  const float* b1h = b1 + (size_t)h * FF + fc * 128 + w * 32;
  const float* w2h = W2 + (size_t)h * FF + fc * 128 + w * 32;
  float b1v[2], w2v[2];
  b1v[0] = b1h[c];      b1v[1] = b1h[16 + c];
  w2v[0] = w2h[c];      w2v[1] = w2h[16 + c];
  asm volatile("" :: "v"(b1v[0]), "v"(b1v[1]), "v"(w2v[0]), "v"(w2v[1]));

  auto stage = [&](int buf, int kc2) {
    load_lds16(aSrc + kc2 * 32, As[buf] + (size_t)(w * 64 + lane) * 8);
    const unsigned short* bk = bBase + kc2 * 512;
    load_lds16(bk,            Bs[buf] + (size_t)((w * 2 + 0) * 64 + lane) * 8);
    load_lds16(bk + 16384,    Bs[buf] + (size_t)((w * 2 + 1) * 64 + lane) * 8);
  };
  auto compute = [&](int buf) {
    bf16x8 a[4], b[2];
#pragma unroll
    for (int mt = 0; mt < 4; ++mt)
      a[mt] = *(const bf16x8*)(As[buf] + (size_t)(mt * 64 + lane) * 8);
#pragma unroll
    for (int t = 0; t < 2; ++t)
      b[t] = *(const bf16x8*)(Bs[buf] + (size_t)((w * 2 + t) * 64 + lane) * 8);
    __builtin_amdgcn_s_setprio(1);
#pragma unroll
    for (int mt = 0; mt < 4; ++mt)
#pragma unroll
      for (int t = 0; t < 2; ++t)
        acc[mt][t] = __builtin_amdgcn_mfma_f32_16x16x32_bf16(a[mt], b[t], acc[mt][t], 0, 0, 0);
    __builtin_amdgcn_s_setprio(0);
  };

  stage(0, 0);
  stage(1, 1);
  for (int i = 0; i < 30; ++i) {
    stage((i + 2) & 3, i + 2);
    asm volatile("s_waitcnt vmcnt(6)" ::: "memory");
    __builtin_amdgcn_s_barrier();
    compute(i & 3);
    asm volatile("" ::: "memory");
  }
  asm volatile("s_waitcnt vmcnt(3)" ::: "memory");
  __builtin_amdgcn_s_barrier();
  compute(2);
  asm volatile("" ::: "memory");
  asm volatile("s_waitcnt vmcnt(0)" ::: "memory");
  __builtin_amdgcn_s_barrier();
  compute(3);

  // Epilogue: per lane cols n = fc*128 + w*32 + t*16 + c
#pragma unroll
  for (int mt = 0; mt < 4; ++mt)
#pragma unroll
    for (int r = 0; r < 4; ++r) {
      float s = 0.0f;
#pragma unroll
      for (int t = 0; t < 2; ++t)
        s += gelu_f(acc[mt][t][r] + b1v[t]) * w2v[t];
      s += __shfl_xor(s, 1);
      s += __shfl_xor(s, 2);
      s += __shfl_xor(s, 4);
      s += __shfl_xor(s, 8);
      if (c == 0) red[w][mt * 16 + q * 4 + r] = s;
    }
  __syncthreads();

  if (tid < 64) {
    int t = stok[tid];
    if (t >= 0) {
      float s = red[0][tid] + red[1][tid] + red[2][tid] + red[3][tid];
      atomicAdd(&out[t], s);
    }
  }
}

// ---------------------------------------------------------------------------
extern "C" void kernel_launch(void* const* d_in, const int* in_sizes, int n_in,
                              void* d_out, int out_size, void* d_ws, size_t ws_size,
                              hipStream_t stream) {
  const int*   selfies = (const int*)d_in[0];
  const int*   tasks   = (const int*)d_in[1];
  const float* values  = (const float*)d_in[2];
  const int*   pmask   = (const int*)d_in[3];
  const float* emb_s   = (const float*)d_in[4];
  const float* emb_t   = (const float*)d_in[5];
  const float* val_vec = (const float*)d_in[6];
  const float* Ws      = (const float*)d_in[7];
  const float* bs      = (const float*)d_in[8];
  const float* W1      = (const float*)d_in[9];
  const float* b1      = (const float*)d_in[10];
  const float* W2      = (const float*)d_in[11];
  const float* b2      = (const float*)d_in[12];
  float* out = (float*)d_out;

  // Workspace layout (all 256-B aligned):
  //   Xb        bf16 [4096][1024]            8 MB
  //   shared_bf bf16 [4096][1024]            8 MB
  //   Wsp       bf16 frag-major              2 MB
  //   W1p       bf16 frag-major             64 MB
  //   counts    int[16] ; lists int[16*4096]
  char* ws = (char*)d_ws;
  unsigned short* Xb        = (unsigned short*)ws;
  unsigned short* shared_bf = (unsigned short*)(ws + (8u << 20));
  unsigned short* Wsp       = (unsigned short*)(ws + (16u << 20));
  unsigned short* W1p       = (unsigned short*)(ws + (18u << 20));
  int* counts = (int*)(ws + (82u << 20));
  int* lists  = (int*)(ws + (82u << 20) + 256);

  hipMemsetAsync(counts, 0, NH * sizeof(int), stream);
  prep_all<<<PW_BLKS + PX_BLKS + TOK / 256, 256, 0, stream>>>(
      selfies, tasks, values, pmask, emb_s, emb_t, val_vec, Ws, W1, b2,
      Xb, Wsp, W1p, counts, lists, out);
  gemm1_mfma<<<dim3(TOK / 64, DD / 128), 256, 0, stream>>>(Xb, Wsp, bs, shared_bf);
  gemm2_mfma<<<2048, 256, 0, stream>>>(shared_bf, W1p, b1, W2,
                                       counts, lists, out);
}